// Round 11
// baseline (171.580 us; speedup 1.0000x reference)
//
#include <hip/hip_runtime.h>
#include <math.h>
#include <stdint.h>

// B=4, H=16, N=4096, D=128 -> 64 independent scan rows of length 4096.
static constexpr int ROWS = 64;
static constexpr int NSEQ = 4096;
static constexpr int DIM  = 128;
static constexpr int SC   = 8;               // scalar sub-chunk length
static constexpr int SPR  = NSEQ / SC;       // 512 sub-chunks per row
static constexpr int NSC  = ROWS * SPR;      // 32768 sub-chunks
static constexpr int VC   = 64;              // vector chunk length
static constexpr int VPR  = NSEQ / VC;       // 64 chunks per row
static constexpr int NVC  = ROWS * VPR;      // 4096 vector chunks
static constexpr int SPC  = VC / SC;         // sub-chunks per vector chunk = 8

typedef __attribute__((address_space(3))) uint32_t  lds_u32;
typedef const __attribute__((address_space(1))) uint32_t g_u32;

// ---------------------------------------------------------------------------
// k_alpha v9: ZERO-BARRIER free-running per-wave pipeline (anti-convoy).
// Every prior variant bulk-synced all resident waves (syncthreads+vmcnt(0)
// drains or short lockstep blocks) -> convoy: the CU alternates all-waiting /
// brief-compute, so average in-flight collapses (2.7-2.9 TB/s wall across 6
// structures). The fast kernels (k_agg/k_out ~6.5 TB/s) share one property:
// no barriers, waves free-run. v9: each wave owns a private 8KB LDS slice
// (2 bufs x (2KB q + 2KB k)) and 64 consecutive timesteps = 16 tiles of 4t.
// Per tile: counted s_waitcnt vmcnt(4) (tile j landed, j+1 still flying) ->
// ds_read dot -> stage tile j+2. No __syncthreads anywhere; all global
// stores deferred to the epilogue so vmcnt tracks ONLY stage loads (T4).
// 1024 blocks x 4 waves = 16 waves/CU, each at its own pipeline phase.
// ---------------------------------------------------------------------------
__global__ __launch_bounds__(256) void k_alpha(
    const float* __restrict__ q, const float* __restrict__ k,
    float* __restrict__ alpha, float* __restrict__ cM, float* __restrict__ cD)
{
    __shared__ float lds[4 * 2048];          // 4 waves x (2 bufs x 1024 floats)
    const int tid  = threadIdx.x;
    const int l    = tid & 63;
    const int w    = tid >> 6;               // wave 0..3
    const int x    = l & 15;                 // dim-block within timestep
    const int gr   = l >> 4;                 // timestep-within-tile (0..3)
    const int wgid = blockIdx.x * 4 + w;     // wave id 0..4095 (64 timesteps)
    const float* qw = q + (size_t)wgid * (64 * DIM);
    const float* kw = k + (size_t)wgid * (64 * DIM);
    const int wl = w * 2048;                 // wave's LDS float base

    float aT[16], sM[8], sD[8];              // epilogue-deferred outputs

    // stage tile J (4 timesteps: q 2KB + k 2KB) into buf (J&1).
    // LDS dest is wave-uniform base; HW adds lane*16 -> linear layout.
    #define STAGE(J)                                                          \
        do {                                                                  \
            const int _b = wl + ((J) & 1) * 1024;                             \
            _Pragma("unroll")                                                 \
            for (int r = 0; r < 2; ++r) {                                     \
                __builtin_amdgcn_global_load_lds(                             \
                    (g_u32*)(qw + (J) * 512 + r * 256 + l * 4),               \
                    (lds_u32*)&lds[_b + r * 256], 16, 0, 0);                  \
                __builtin_amdgcn_global_load_lds(                             \
                    (g_u32*)(kw + (J) * 512 + r * 256 + l * 4),               \
                    (lds_u32*)&lds[_b + 512 + r * 256], 16, 0, 0);            \
            }                                                                 \
        } while (0)

    STAGE(0);
    STAGE(1);

    float aPrev = 0.f;
    #pragma unroll
    for (int j = 0; j < 16; ++j) {
        if (j < 15) asm volatile("s_waitcnt vmcnt(4)" ::: "memory");
        else        asm volatile("s_waitcnt vmcnt(0)" ::: "memory");
        const float* tb = &lds[wl + (j & 1) * 1024];
        // lane (gr,x): timestep gr, dims x*8..x*8+7 (2x ds_read_b128 each)
        const float4 q0 = *(const float4*)(tb + gr * 128 + x * 8);
        const float4 q1 = *(const float4*)(tb + gr * 128 + x * 8 + 4);
        const float4 k0 = *(const float4*)(tb + 512 + gr * 128 + x * 8);
        const float4 k1 = *(const float4*)(tb + 512 + gr * 128 + x * 8 + 4);
        float p = q0.x*k0.x + q0.y*k0.y + q0.z*k0.z + q0.w*k0.w
                + q1.x*k1.x + q1.y*k1.y + q1.z*k1.z + q1.w*k1.w;
        p += __shfl_xor(p, 1);
        p += __shfl_xor(p, 2);
        p += __shfl_xor(p, 4);
        p += __shfl_xor(p, 8);               // all 16 lanes of group hold alpha_t
        aT[j] = p;
        __builtin_amdgcn_sched_barrier(0);   // reads consumed before restage
        if (j < 14) STAGE(j + 2);            // overwrite buf j&1 (reads done)
        if (j & 1) {                         // close sub-chunk (8 timesteps)
            float M = fmaxf(aPrev, p);
            M = fmaxf(M, __shfl_xor(M, 16));
            M = fmaxf(M, __shfl_xor(M, 32)); // max over 8 alphas
            float e = __expf(aPrev - M) + __expf(p - M);
            e += __shfl_xor(e, 16);
            e += __shfl_xor(e, 32);          // sum over the 4 groups
            sM[j >> 1] = M; sD[j >> 1] = e;
        }
        aPrev = p;
    }
    #undef STAGE

    // epilogue: the only global stores in the kernel
    #pragma unroll
    for (int j = 0; j < 16; ++j)
        if (x == 0) alpha[wgid * 64 + j * 4 + gr] = aT[j];
    if (l == 0) {
        #pragma unroll
        for (int p2 = 0; p2 < 8; ++p2) {
            cM[wgid * 8 + p2] = sM[p2];
            cD[wgid * 8 + p2] = sD[p2];
        }
    }
}

// ---------------------------------------------------------------------------
// k_scan: per row (64 blocks):
//  1) thread-0 serial exclusive scan over 512 sub-chunks -> pM,pD (+LDS copy)
//  2) 8-lane-group prefix-max scan per sub-chunk -> coefCW[t] = (c_t, w_t)
// ---------------------------------------------------------------------------
__global__ __launch_bounds__(256) void k_scan(
    const float* __restrict__ alpha, const float* __restrict__ cM,
    const float* __restrict__ cD,
    float* __restrict__ pM, float* __restrict__ pD, float2* __restrict__ coefCW)
{
    __shared__ float lM[SPR], lD[SPR], lpM[SPR];
    const int row = blockIdx.x;
    const int tid = threadIdx.x;

    lM[tid]       = cM[row * SPR + tid];
    lM[tid + 256] = cM[row * SPR + tid + 256];
    lD[tid]       = cD[row * SPR + tid];
    lD[tid + 256] = cD[row * SPR + tid + 256];
    __syncthreads();

    if (tid == 0) {
        float m = -INFINITY, d = 0.f;
        for (int sl = 0; sl < SPR; ++sl) {
            lpM[sl] = m;
            pM[row * SPR + sl] = m; pD[row * SPR + sl] = d;
            const float M = lM[sl], D = lD[sl];
            const float mn = fmaxf(m, M);
            d = d * __expf(m - mn) + D * __expf(M - mn);
            m = mn;
        }
    }
    __syncthreads();

    const int li = tid & 7, grp = tid >> 3;           // 32 groups of 8 lanes
    for (int sl = grp; sl < SPR; sl += 32) {
        const int s = row * SPR + sl;
        const float a = alpha[s * SC + li];
        // inclusive prefix max over the 8 lanes
        float m = a;
        #pragma unroll
        for (int d = 1; d < 8; d <<= 1) {
            const float o = __shfl_up(m, d, 8);
            if (li >= d) m = fmaxf(m, o);
        }
        const float carry = lpM[sl];
        const float mf = fmaxf(m, carry);             // running max incl. carry
        float mp = __shfl_up(mf, 1, 8);
        if (li == 0) mp = carry;                      // m_{t-1}
        const float cc = __expf(mp - mf);             // exp(-inf)=0 at very start
        const float wt = __expf(a - mf);
        coefCW[s * SC + li] = make_float2(cc, wt);
    }
}

// ---------------------------------------------------------------------------
// k_agg: per vector chunk (one wave, lane owns 2 dims): n'_C via the global
// coefficient recurrence seeded 0 (result normalized at chunk-end global max).
// ---------------------------------------------------------------------------
__global__ __launch_bounds__(256) void k_agg(
    const float* __restrict__ v, const float2* __restrict__ coefCW,
    float2* __restrict__ aggN)
{
    const int lane  = threadIdx.x & 63;
    const int C     = blockIdx.x * 4 + (threadIdx.x >> 6);
    const int vbase = C * (VC * DIM);
    const int cbase = __builtin_amdgcn_readfirstlane(C * VC);

    float nx = 0.f, ny = 0.f;
    for (int t0 = 0; t0 < VC; t0 += 8) {
        float2 cw[8], vv[8];
        #pragma unroll
        for (int u = 0; u < 8; ++u) cw[u] = coefCW[cbase + t0 + u];
        #pragma unroll
        for (int u = 0; u < 8; ++u)
            vv[u] = *((const float2*)(v + vbase + (t0 + u) * DIM) + lane);
        #pragma unroll
        for (int u = 0; u < 8; ++u) {
            nx = cw[u].x * nx + cw[u].y * vv[u].x;
            ny = cw[u].x * ny + cw[u].y * vv[u].y;
        }
    }
    aggN[C * (DIM / 2) + lane] = make_float2(nx, ny);
}

// ---------------------------------------------------------------------------
// k_pref: per row, exclusive prefix scan of aggN over 64 chunks (in place),
// combine factor f1 = exp(pM[8C] - pM[8C+8]) (sub-chunk stride = 8).
// ---------------------------------------------------------------------------
__global__ __launch_bounds__(128) void k_pref(
    float* __restrict__ aggN, const float* __restrict__ pM)
{
    const int row = blockIdx.x;
    const int d   = threadIdx.x;
    float state = 0.f;
    for (int C0 = 0; C0 < VPR; C0 += 8) {
        float nb[8], f1[8];
        #pragma unroll
        for (int u = 0; u < 8; ++u) {
            const int C  = C0 + u;
            const int Cg = row * VPR + C;
            nb[u] = aggN[Cg * DIM + d];
            const bool last = (C == VPR - 1);
            const float mp  = pM[SPC * Cg];
            const float mp2 = last ? 0.f : pM[SPC * Cg + SPC];
            f1[u] = last ? 0.f : __expf(mp - mp2);
        }
        #pragma unroll
        for (int u = 0; u < 8; ++u) {
            const float nc = nb[u];
            aggN[(row * VPR + C0 + u) * DIM + d] = state;
            state = state * f1[u] + nc;
        }
    }
}

// ---------------------------------------------------------------------------
// k_out: per vector chunk (one wave, lane owns 2 dims): replay the global
// recurrence seeded with the exclusive prefixes; y_t = n_t * rcp(d_t).
// ---------------------------------------------------------------------------
__global__ __launch_bounds__(256) void k_out(
    const float* __restrict__ v, const float2* __restrict__ coefCW,
    const float2* __restrict__ preN, const float* __restrict__ pD,
    float* __restrict__ y)
{
    const int lane  = threadIdx.x & 63;
    const int C     = blockIdx.x * 4 + (threadIdx.x >> 6);
    const int vbase = C * (VC * DIM);
    const int cbase = __builtin_amdgcn_readfirstlane(C * VC);

    float2 n  = preN[C * (DIM / 2) + lane];
    float dch = pD[SPC * C];

    for (int t0 = 0; t0 < VC; t0 += 8) {
        float2 cw[8], vv[8];
        #pragma unroll
        for (int u = 0; u < 8; ++u) cw[u] = coefCW[cbase + t0 + u];
        #pragma unroll
        for (int u = 0; u < 8; ++u)
            vv[u] = *((const float2*)(v + vbase + (t0 + u) * DIM) + lane);
        #pragma unroll
        for (int u = 0; u < 8; ++u) {
            n.x = cw[u].x * n.x + cw[u].y * vv[u].x;
            n.y = cw[u].x * n.y + cw[u].y * vv[u].y;
            dch = cw[u].x * dch + cw[u].y;
            const float rd = __builtin_amdgcn_rcpf(dch);
            *((float2*)(y + vbase + (t0 + u) * DIM) + lane) =
                make_float2(n.x * rd, n.y * rd);
        }
    }
}

// ---------------------------------------------------------------------------
extern "C" void kernel_launch(void* const* d_in, const int* in_sizes, int n_in,
                              void* d_out, int out_size, void* d_ws, size_t ws_size,
                              hipStream_t stream) {
    const float* q = (const float*)d_in[0];
    const float* k = (const float*)d_in[1];
    const float* v = (const float*)d_in[2];
    float* y  = (float*)d_out;
    float* ws = (float*)d_ws;

    // ws layout (floats):
    //  coefCW : 524288    (float2[262144], global per-timestep (c,w))
    //  pM,pD  : 32768 each (exclusive scalar prefixes, SC=8 grain)
    //  cM,cD  : 32768 each (sub-chunk local max / denom)
    //  U      : 524288    (alpha uses first 262144; aggN reuses all of it)
    float*  coefCWf = ws;
    float*  pM      = coefCWf + 2 * ROWS * NSEQ;       // +524288
    float*  pD      = pM + NSC;
    float*  cM      = pD + NSC;
    float*  cD      = cM + NSC;
    float*  U       = cD + NSC;
    float*  alphaA  = U;                               // 262144 floats
    float*  aggNf   = U;                               // 524288 floats (after k_scan)
    float2* coefCW  = (float2*)coefCWf;
    float2* aggN2   = (float2*)aggNf;
    // total: 1,179,648 floats = 4.72 MB

    k_alpha<<<1024, 256, 0, stream>>>(q, k, alphaA, cM, cD);
    k_scan<<<ROWS, 256, 0, stream>>>(alphaA, cM, cD, pM, pD, coefCW);
    k_agg<<<NVC / 4, 256, 0, stream>>>(v, coefCW, aggN2);
    k_pref<<<ROWS, DIM, 0, stream>>>(aggNf, pM);
    k_out<<<NVC / 4, 256, 0, stream>>>(v, coefCW, aggN2, pD, y);
}

// Round 12
// 171.241 us; speedup vs baseline: 1.0020x; 1.0020x over previous
//
#include <hip/hip_runtime.h>
#include <math.h>
#include <stdint.h>

// B=4, H=16, N=4096, D=128 -> 64 independent scan rows of length 4096.
static constexpr int ROWS = 64;
static constexpr int NSEQ = 4096;
static constexpr int DIM  = 128;
static constexpr int SC   = 8;               // scalar sub-chunk length
static constexpr int SPR  = NSEQ / SC;       // 512 sub-chunks per row
static constexpr int NSC  = ROWS * SPR;      // 32768 sub-chunks
static constexpr int VC   = 64;              // vector chunk length
static constexpr int VPR  = NSEQ / VC;       // 64 chunks per row
static constexpr int NVC  = ROWS * VPR;      // 4096 vector chunks
static constexpr int SPC  = VC / SC;         // sub-chunks per vector chunk = 8

typedef __attribute__((address_space(3))) uint32_t  lds_u32;
typedef const __attribute__((address_space(1))) uint32_t g_u32;

// ---------------------------------------------------------------------------
// k_alpha v10: WAVE-PER-STREAM specialization. All 7 prior variants had every
// wave interleave q-requests and k-requests (the one property the ~6.8 TB/s
// kernels lack: their waves stream ONE contiguous run). v10: block = one
// 32-timestep tile; waves 0-1 stage the q-panel (8KB contiguous each, 8x
// gload_lds dwordx4), waves 2-3 stage the k-panel. Each wave's VMEM string is
// a pure single-stream contiguous run. One barrier, then v7-proven swizzled
// LDS compute (8 lanes/timestep, 3-shfl fold); per-wave SC=8 stats (no
// cross-wave fold). LDS 32KB -> 5 blocks/CU = 20 waves/CU.
// LDS linear dest + involution-swizzled source + swizzled read (rule 21,
// correctness-proven in v7/v8).
// ---------------------------------------------------------------------------
__global__ __launch_bounds__(256) void k_alpha(
    const float* __restrict__ q, const float* __restrict__ k,
    float* __restrict__ alpha, float* __restrict__ cM, float* __restrict__ cD)
{
    __shared__ float qs[4096];               // 16KB: 32 rows x 512B
    __shared__ float ks[4096];
    const int tid  = threadIdx.x;
    const int l    = tid & 63;
    const int w    = tid >> 6;               // wave 0..3
    const int tile = blockIdx.x;             // 32-timestep tile
    const size_t base = (size_t)tile * (32 * DIM);

    // ---- wave-specialized staging: waves 0-1 stream q, waves 2-3 stream k.
    if (w < 2) {
        #pragma unroll
        for (int i = 0; i < 8; ++i) {
            const int p  = w * 8192 + i * 1024 + l * 16;     // linear LDS byte
            const int ps = p ^ (((p >> 9) & 7) << 4);        // involution swz
            __builtin_amdgcn_global_load_lds((g_u32*)(q + base + (ps >> 2)),
                (lds_u32*)&qs[(w * 8192 + i * 1024) >> 2], 16, 0, 0);
        }
    } else {
        #pragma unroll
        for (int i = 0; i < 8; ++i) {
            const int p  = (w - 2) * 8192 + i * 1024 + l * 16;
            const int ps = p ^ (((p >> 9) & 7) << 4);
            __builtin_amdgcn_global_load_lds((g_u32*)(k + base + (ps >> 2)),
                (lds_u32*)&ks[((w - 2) * 8192 + i * 1024) >> 2], 16, 0, 0);
        }
    }
    __syncthreads();   // each wave drains only ITS stream's vmcnt, then barrier

    // ---- compute: t = tid>>3 (8 lanes per timestep, 16 floats each)
    const int t  = tid >> 3;                 // timestep 0..31 (wave w owns 8)
    const int x  = tid & 7;
    const int sw = (t & 7) << 4;
    float acc = 0.f;
    #pragma unroll
    for (int j = 0; j < 4; ++j) {
        const int off = t * 512 + ((x * 64 + j * 16) ^ sw);  // swizzled read
        const float4 qv = *(const float4*)((const char*)qs + off);
        const float4 kv = *(const float4*)((const char*)ks + off);
        acc += qv.x * kv.x + qv.y * kv.y + qv.z * kv.z + qv.w * kv.w;
    }
    acc += __shfl_xor(acc, 1);
    acc += __shfl_xor(acc, 2);
    acc += __shfl_xor(acc, 4);               // 8 lanes of t-group hold alpha_t

    // per-wave stats over its 8 timesteps (sub-chunk = tile*4 + w)
    float M = acc;
    M = fmaxf(M, __shfl_xor(M, 8));
    M = fmaxf(M, __shfl_xor(M, 16));
    M = fmaxf(M, __shfl_xor(M, 32));
    float e = (x == 0) ? __expf(acc - M) : 0.f;
    e += __shfl_xor(e, 8);
    e += __shfl_xor(e, 16);
    e += __shfl_xor(e, 32);

    if (x == 0) alpha[tile * 32 + t] = acc;
    if (l == 0) {
        const int s = tile * 4 + w;          // SC=8 sub-chunk id
        cM[s] = M; cD[s] = e;
    }
}

// ---------------------------------------------------------------------------
// k_scan: per row (64 blocks):
//  1) thread-0 serial exclusive scan over 512 sub-chunks -> pM,pD (+LDS copy)
//  2) 8-lane-group prefix-max scan per sub-chunk -> coefCW[t] = (c_t, w_t)
// ---------------------------------------------------------------------------
__global__ __launch_bounds__(256) void k_scan(
    const float* __restrict__ alpha, const float* __restrict__ cM,
    const float* __restrict__ cD,
    float* __restrict__ pM, float* __restrict__ pD, float2* __restrict__ coefCW)
{
    __shared__ float lM[SPR], lD[SPR], lpM[SPR];
    const int row = blockIdx.x;
    const int tid = threadIdx.x;

    lM[tid]       = cM[row * SPR + tid];
    lM[tid + 256] = cM[row * SPR + tid + 256];
    lD[tid]       = cD[row * SPR + tid];
    lD[tid + 256] = cD[row * SPR + tid + 256];
    __syncthreads();

    if (tid == 0) {
        float m = -INFINITY, d = 0.f;
        for (int sl = 0; sl < SPR; ++sl) {
            lpM[sl] = m;
            pM[row * SPR + sl] = m; pD[row * SPR + sl] = d;
            const float M = lM[sl], D = lD[sl];
            const float mn = fmaxf(m, M);
            d = d * __expf(m - mn) + D * __expf(M - mn);
            m = mn;
        }
    }
    __syncthreads();

    const int li = tid & 7, grp = tid >> 3;           // 32 groups of 8 lanes
    for (int sl = grp; sl < SPR; sl += 32) {
        const int s = row * SPR + sl;
        const float a = alpha[s * SC + li];
        // inclusive prefix max over the 8 lanes
        float m = a;
        #pragma unroll
        for (int d = 1; d < 8; d <<= 1) {
            const float o = __shfl_up(m, d, 8);
            if (li >= d) m = fmaxf(m, o);
        }
        const float carry = lpM[sl];
        const float mf = fmaxf(m, carry);             // running max incl. carry
        float mp = __shfl_up(mf, 1, 8);
        if (li == 0) mp = carry;                      // m_{t-1}
        const float cc = __expf(mp - mf);             // exp(-inf)=0 at very start
        const float wt = __expf(a - mf);
        coefCW[s * SC + li] = make_float2(cc, wt);
    }
}

// ---------------------------------------------------------------------------
// k_agg: per vector chunk (one wave, lane owns 2 dims): n'_C via the global
// coefficient recurrence seeded 0 (result normalized at chunk-end global max).
// ---------------------------------------------------------------------------
__global__ __launch_bounds__(256) void k_agg(
    const float* __restrict__ v, const float2* __restrict__ coefCW,
    float2* __restrict__ aggN)
{
    const int lane  = threadIdx.x & 63;
    const int C     = blockIdx.x * 4 + (threadIdx.x >> 6);
    const int vbase = C * (VC * DIM);
    const int cbase = __builtin_amdgcn_readfirstlane(C * VC);

    float nx = 0.f, ny = 0.f;
    for (int t0 = 0; t0 < VC; t0 += 8) {
        float2 cw[8], vv[8];
        #pragma unroll
        for (int u = 0; u < 8; ++u) cw[u] = coefCW[cbase + t0 + u];
        #pragma unroll
        for (int u = 0; u < 8; ++u)
            vv[u] = *((const float2*)(v + vbase + (t0 + u) * DIM) + lane);
        #pragma unroll
        for (int u = 0; u < 8; ++u) {
            nx = cw[u].x * nx + cw[u].y * vv[u].x;
            ny = cw[u].x * ny + cw[u].y * vv[u].y;
        }
    }
    aggN[C * (DIM / 2) + lane] = make_float2(nx, ny);
}

// ---------------------------------------------------------------------------
// k_pref: per row, exclusive prefix scan of aggN over 64 chunks (in place),
// combine factor f1 = exp(pM[8C] - pM[8C+8]) (sub-chunk stride = 8).
// ---------------------------------------------------------------------------
__global__ __launch_bounds__(128) void k_pref(
    float* __restrict__ aggN, const float* __restrict__ pM)
{
    const int row = blockIdx.x;
    const int d   = threadIdx.x;
    float state = 0.f;
    for (int C0 = 0; C0 < VPR; C0 += 8) {
        float nb[8], f1[8];
        #pragma unroll
        for (int u = 0; u < 8; ++u) {
            const int C  = C0 + u;
            const int Cg = row * VPR + C;
            nb[u] = aggN[Cg * DIM + d];
            const bool last = (C == VPR - 1);
            const float mp  = pM[SPC * Cg];
            const float mp2 = last ? 0.f : pM[SPC * Cg + SPC];
            f1[u] = last ? 0.f : __expf(mp - mp2);
        }
        #pragma unroll
        for (int u = 0; u < 8; ++u) {
            const float nc = nb[u];
            aggN[(row * VPR + C0 + u) * DIM + d] = state;
            state = state * f1[u] + nc;
        }
    }
}

// ---------------------------------------------------------------------------
// k_out: per vector chunk (one wave, lane owns 2 dims): replay the global
// recurrence seeded with the exclusive prefixes; y_t = n_t * rcp(d_t).
// ---------------------------------------------------------------------------
__global__ __launch_bounds__(256) void k_out(
    const float* __restrict__ v, const float2* __restrict__ coefCW,
    const float2* __restrict__ preN, const float* __restrict__ pD,
    float* __restrict__ y)
{
    const int lane  = threadIdx.x & 63;
    const int C     = blockIdx.x * 4 + (threadIdx.x >> 6);
    const int vbase = C * (VC * DIM);
    const int cbase = __builtin_amdgcn_readfirstlane(C * VC);

    float2 n  = preN[C * (DIM / 2) + lane];
    float dch = pD[SPC * C];

    for (int t0 = 0; t0 < VC; t0 += 8) {
        float2 cw[8], vv[8];
        #pragma unroll
        for (int u = 0; u < 8; ++u) cw[u] = coefCW[cbase + t0 + u];
        #pragma unroll
        for (int u = 0; u < 8; ++u)
            vv[u] = *((const float2*)(v + vbase + (t0 + u) * DIM) + lane);
        #pragma unroll
        for (int u = 0; u < 8; ++u) {
            n.x = cw[u].x * n.x + cw[u].y * vv[u].x;
            n.y = cw[u].x * n.y + cw[u].y * vv[u].y;
            dch = cw[u].x * dch + cw[u].y;
            const float rd = __builtin_amdgcn_rcpf(dch);
            *((float2*)(y + vbase + (t0 + u) * DIM) + lane) =
                make_float2(n.x * rd, n.y * rd);
        }
    }
}

// ---------------------------------------------------------------------------
extern "C" void kernel_launch(void* const* d_in, const int* in_sizes, int n_in,
                              void* d_out, int out_size, void* d_ws, size_t ws_size,
                              hipStream_t stream) {
    const float* q = (const float*)d_in[0];
    const float* k = (const float*)d_in[1];
    const float* v = (const float*)d_in[2];
    float* y  = (float*)d_out;
    float* ws = (float*)d_ws;

    // ws layout (floats):
    //  coefCW : 524288    (float2[262144], global per-timestep (c,w))
    //  pM,pD  : 32768 each (exclusive scalar prefixes, SC=8 grain)
    //  cM,cD  : 32768 each (sub-chunk local max / denom)
    //  U      : 524288    (alpha uses first 262144; aggN reuses all of it)
    float*  coefCWf = ws;
    float*  pM      = coefCWf + 2 * ROWS * NSEQ;       // +524288
    float*  pD      = pM + NSC;
    float*  cM      = pD + NSC;
    float*  cD      = cM + NSC;
    float*  U       = cD + NSC;
    float*  alphaA  = U;                               // 262144 floats
    float*  aggNf   = U;                               // 524288 floats (after k_scan)
    float2* coefCW  = (float2*)coefCWf;
    float2* aggN2   = (float2*)aggNf;
    // total: 1,179,648 floats = 4.72 MB

    k_alpha<<<ROWS * NSEQ / 32, 256, 0, stream>>>(q, k, alphaA, cM, cD);
    k_scan<<<ROWS, 256, 0, stream>>>(alphaA, cM, cD, pM, pD, coefCW);
    k_agg<<<NVC / 4, 256, 0, stream>>>(v, coefCW, aggN2);
    k_pref<<<ROWS, DIM, 0, stream>>>(aggNf, pM);
    k_out<<<NVC / 4, 256, 0, stream>>>(v, coefCW, aggN2, pD, y);
}